// Round 1
// baseline (1306.148 us; speedup 1.0000x reference)
//
#include <hip/hip_runtime.h>
#include <cstddef>

#define N_NODES 100000
#define E_EDGES 1600000
#define NFEAT   602
#define NHID    128
#define NCLASS  41
#define LN_EPS  1e-5f

// ---------------------------------------------------------------------------
// Tiled fp32 GEMM: C[M x 128] = A[M x K] @ W[K x 128]
// 64 rows x 128 cols per block (256 threads), K tiles of 16.
// Each thread: acc[8][4] (rows rowg*8+i, cols col..col+3).
// ---------------------------------------------------------------------------
__global__ __launch_bounds__(256) void k_gemm_nc128(
    const float* __restrict__ A, const float* __restrict__ W,
    float* __restrict__ C, int M, int K)
{
    __shared__ float xs[16][64];
    __shared__ float ws[16][128];
    const int tid = threadIdx.x;
    const int rowBase = blockIdx.x * 64;
    const int col  = (tid & 31) * 4;
    const int rowg = tid >> 5;      // 0..7
    const int lr = tid >> 2;        // 0..63  (x-tile row)
    const int lk = (tid & 3) * 4;   // 0,4,8,12 (x-tile k)
    const int wr = tid >> 5;        // 0..7   (w-tile k)
    const int wc = (tid & 31) * 4;  // w-tile col

    float acc[8][4];
#pragma unroll
    for (int i = 0; i < 8; ++i)
#pragma unroll
        for (int j = 0; j < 4; ++j) acc[i][j] = 0.f;

    const int nt = (K + 15) / 16;
    for (int t = 0; t < nt; ++t) {
        const int k0 = t * 16;
        // ---- load x tile (64 rows x 16 k), float2 (rows are 8B aligned) ----
        {
            int r = rowBase + lr;
            int rc = (r < M) ? r : (M - 1);
            const float* ap = A + (size_t)rc * K;
            int kk = k0 + lk;
            float2 v01 = make_float2(0.f, 0.f);
            float2 v23 = make_float2(0.f, 0.f);
            if (r < M) {
                if (kk < K)     v01 = *reinterpret_cast<const float2*>(ap + kk);
                if (kk + 2 < K) v23 = *reinterpret_cast<const float2*>(ap + kk + 2);
            }
            xs[lk + 0][lr] = v01.x;
            xs[lk + 1][lr] = v01.y;
            xs[lk + 2][lr] = v23.x;
            xs[lk + 3][lr] = v23.y;
        }
        // ---- load W tile (16 k x 128 cols), float4 ----
#pragma unroll
        for (int h = 0; h < 2; ++h) {
            int kk = k0 + wr + h * 8;
            float4 v = make_float4(0.f, 0.f, 0.f, 0.f);
            if (kk < K) v = *reinterpret_cast<const float4*>(W + (size_t)kk * 128 + wc);
            *reinterpret_cast<float4*>(&ws[wr + h * 8][wc]) = v;
        }
        __syncthreads();
        // ---- compute ----
#pragma unroll
        for (int k = 0; k < 16; ++k) {
            float4 wv = *reinterpret_cast<const float4*>(&ws[k][col]);
            float xr[8];
#pragma unroll
            for (int i = 0; i < 8; ++i) xr[i] = xs[k][rowg * 8 + i];
#pragma unroll
            for (int i = 0; i < 8; ++i) {
                acc[i][0] += xr[i] * wv.x;
                acc[i][1] += xr[i] * wv.y;
                acc[i][2] += xr[i] * wv.z;
                acc[i][3] += xr[i] * wv.w;
            }
        }
        __syncthreads();
    }
    // ---- store ----
#pragma unroll
    for (int i = 0; i < 8; ++i) {
        int r = rowBase + rowg * 8 + i;
        if (r < M) {
            float4 v = make_float4(acc[i][0], acc[i][1], acc[i][2], acc[i][3]);
            *reinterpret_cast<float4*>(C + (size_t)r * 128 + col) = v;
        }
    }
}

// ---------------------------------------------------------------------------
// CSR build: zero, histogram, 3-kernel scan, scatter
// ---------------------------------------------------------------------------
__global__ void k_zero(int* __restrict__ p, int n)
{
    int i = blockIdx.x * blockDim.x + threadIdx.x;
    if (i < n) p[i] = 0;
}

__global__ void k_hist(const int* __restrict__ rows, int* __restrict__ cnt)
{
    int i = blockIdx.x * blockDim.x + threadIdx.x;
    if (i < E_EDGES) atomicAdd(&cnt[rows[i]], 1);
}

__global__ __launch_bounds__(256) void k_blocksum(
    const int* __restrict__ cnt, int* __restrict__ bsum, int n)
{
    __shared__ int sd[256];
    int i = blockIdx.x * 256 + threadIdx.x;
    int v = (i < n) ? cnt[i] : 0;
    sd[threadIdx.x] = v;
    __syncthreads();
    for (int s = 128; s > 0; s >>= 1) {
        if (threadIdx.x < s) sd[threadIdx.x] += sd[threadIdx.x + s];
        __syncthreads();
    }
    if (threadIdx.x == 0) bsum[blockIdx.x] = sd[0];
}

__global__ __launch_bounds__(512) void k_scan_bsum(
    const int* __restrict__ bsum, int* __restrict__ bpre, int nb,
    int* __restrict__ row_ptr)
{
    __shared__ int s[512];
    int t = threadIdx.x;
    int v = (t < nb) ? bsum[t] : 0;
    s[t] = v;
    __syncthreads();
    for (int off = 1; off < 512; off <<= 1) {
        int u = (t >= off) ? s[t - off] : 0;
        __syncthreads();
        s[t] += u;
        __syncthreads();
    }
    if (t < nb) bpre[t] = s[t] - v;   // exclusive
    if (t == 0) row_ptr[N_NODES] = E_EDGES;
}

__global__ __launch_bounds__(256) void k_scan_final(
    const int* __restrict__ cnt, const int* __restrict__ bpre,
    int* __restrict__ row_ptr, int* __restrict__ fill, int n)
{
    __shared__ int s[256];
    int i = blockIdx.x * 256 + threadIdx.x;
    int t = threadIdx.x;
    int v = (i < n) ? cnt[i] : 0;
    s[t] = v;
    __syncthreads();
    for (int off = 1; off < 256; off <<= 1) {
        int u = (t >= off) ? s[t - off] : 0;
        __syncthreads();
        s[t] += u;
        __syncthreads();
    }
    if (i < n) {
        int ex = bpre[blockIdx.x] + s[t] - v;
        row_ptr[i] = ex;
        fill[i] = ex;
    }
}

__global__ void k_scatter(const int* __restrict__ rows, const int* __restrict__ cols,
                          const float* __restrict__ vals, int* __restrict__ fill,
                          int* __restrict__ scol, float* __restrict__ sval)
{
    int i = blockIdx.x * blockDim.x + threadIdx.x;
    if (i < E_EDGES) {
        int r = rows[i];
        int p = atomicAdd(&fill[r], 1);
        scol[p] = cols[i];
        sval[p] = vals[i];
    }
}

// ---------------------------------------------------------------------------
// Fused spmm (CSR gather) + bias + LayerNorm + ReLU.
// One wave (64 lanes) per row; lane handles feats lane and lane+64.
// ---------------------------------------------------------------------------
__global__ __launch_bounds__(256) void k_spmm_ln_relu(
    const float* __restrict__ Hin, const int* __restrict__ row_ptr,
    const int* __restrict__ scol, const float* __restrict__ sval,
    const float* __restrict__ bias, const float* __restrict__ g,
    const float* __restrict__ bb, float* __restrict__ Hout)
{
    const int w = threadIdx.x >> 6;
    const int lane = threadIdx.x & 63;
    const int row = blockIdx.x * 4 + w;
    const int start = row_ptr[row];
    const int end = row_ptr[row + 1];

    float a0 = 0.f, a1 = 0.f;
    int p = start;
    for (; p + 3 < end; p += 4) {
        int c0 = scol[p], c1 = scol[p + 1], c2 = scol[p + 2], c3 = scol[p + 3];
        float v0 = sval[p], v1 = sval[p + 1], v2 = sval[p + 2], v3 = sval[p + 3];
        const float* h0 = Hin + (size_t)c0 * NHID;
        const float* h1 = Hin + (size_t)c1 * NHID;
        const float* h2 = Hin + (size_t)c2 * NHID;
        const float* h3 = Hin + (size_t)c3 * NHID;
        a0 += v0 * h0[lane];      a1 += v0 * h0[64 + lane];
        a0 += v1 * h1[lane];      a1 += v1 * h1[64 + lane];
        a0 += v2 * h2[lane];      a1 += v2 * h2[64 + lane];
        a0 += v3 * h3[lane];      a1 += v3 * h3[64 + lane];
    }
    for (; p < end; ++p) {
        int c = scol[p];
        float v = sval[p];
        a0 += v * Hin[(size_t)c * NHID + lane];
        a1 += v * Hin[(size_t)c * NHID + 64 + lane];
    }
    a0 += bias[lane];
    a1 += bias[64 + lane];

    // LayerNorm over 128 feats (2 per lane, 64-lane wave reduce)
    float sum = a0 + a1, sq = a0 * a0 + a1 * a1;
#pragma unroll
    for (int off = 32; off; off >>= 1) {
        sum += __shfl_xor(sum, off);
        sq  += __shfl_xor(sq, off);
    }
    float mu = sum * (1.f / 128.f);
    float var = sq * (1.f / 128.f) - mu * mu;
    float rs = rsqrtf(var + LN_EPS);
    float y0 = (a0 - mu) * rs * g[lane] + bb[lane];
    float y1 = (a1 - mu) * rs * g[64 + lane] + bb[64 + lane];
    Hout[(size_t)row * NHID + lane]      = fmaxf(y0, 0.f);
    Hout[(size_t)row * NHID + 64 + lane] = fmaxf(y1, 0.f);
}

// ---------------------------------------------------------------------------
// Output: logits = H @ Wout + bout, then log_softmax. One wave per row.
// ---------------------------------------------------------------------------
__global__ __launch_bounds__(256) void k_out(
    const float* __restrict__ H, const float* __restrict__ Wout,
    const float* __restrict__ bout, float* __restrict__ out)
{
    __shared__ float ws[NHID * NCLASS];   // 128*41
    __shared__ float bs[NCLASS];
    __shared__ float hrow[4][NHID];
    for (int i = threadIdx.x; i < NHID * NCLASS; i += 256) ws[i] = Wout[i];
    if (threadIdx.x < NCLASS) bs[threadIdx.x] = bout[threadIdx.x];

    const int w = threadIdx.x >> 6;
    const int lane = threadIdx.x & 63;
    const int row = blockIdx.x * 4 + w;
    hrow[w][lane]      = H[(size_t)row * NHID + lane];
    hrow[w][64 + lane] = H[(size_t)row * NHID + 64 + lane];
    __syncthreads();

    float acc = (lane < NCLASS) ? bs[lane] : 0.f;
    if (lane < NCLASS) {
#pragma unroll 8
        for (int k = 0; k < NHID; ++k) acc += hrow[w][k] * ws[k * NCLASS + lane];
    }
    float x = (lane < NCLASS) ? acc : -1e30f;
    float m = x;
#pragma unroll
    for (int off = 32; off; off >>= 1) m = fmaxf(m, __shfl_xor(m, off));
    float e = (lane < NCLASS) ? expf(x - m) : 0.f;
    float se = e;
#pragma unroll
    for (int off = 32; off; off >>= 1) se += __shfl_xor(se, off);
    if (lane < NCLASS) out[(size_t)row * NCLASS + lane] = x - m - logf(se);
}

// ---------------------------------------------------------------------------
extern "C" void kernel_launch(void* const* d_in, const int* in_sizes, int n_in,
                              void* d_out, int out_size, void* d_ws, size_t ws_size,
                              hipStream_t stream)
{
    const float* x    = (const float*)d_in[0];
    const int*   rows = (const int*)  d_in[1];
    const int*   cols = (const int*)  d_in[2];
    const float* vals = (const float*)d_in[3];
    const float* W1   = (const float*)d_in[4];
    const float* b1   = (const float*)d_in[5];
    const float* W2   = (const float*)d_in[6];
    const float* b2   = (const float*)d_in[7];
    const float* W3   = (const float*)d_in[8];
    const float* b3   = (const float*)d_in[9];
    const float* ln_g = (const float*)d_in[10];
    const float* ln_b = (const float*)d_in[11];
    const float* Wout = (const float*)d_in[12];
    const float* bout = (const float*)d_in[13];
    float* out = (float*)d_out;

    // workspace layout
    float* HA = (float*)d_ws;                               // N*128 f32
    float* HB = HA + (size_t)N_NODES * NHID;                // N*128 f32
    int* cnt     = (int*)(HB + (size_t)N_NODES * NHID);     // N
    int* row_ptr = cnt + N_NODES;                           // N+1
    int* fill    = row_ptr + N_NODES + 1;                   // N+1
    int* bsum    = fill + N_NODES + 1;                      // 512
    int* bpre    = bsum + 512;                              // 512
    int* scol    = bpre + 512;                              // E
    float* sval  = (float*)(scol + E_EDGES);                // E

    const int nbScan = (N_NODES + 255) / 256;               // 391
    const int gE = (E_EDGES + 255) / 256;                   // 6250
    const int gGemm = (N_NODES + 63) / 64;                  // 1563
    const int gRow = N_NODES / 4;                           // 25000 (exact)

    auto build_csr = [&](int gph) {
        k_zero<<<nbScan, 256, 0, stream>>>(cnt, N_NODES);
        k_hist<<<gE, 256, 0, stream>>>(rows + (size_t)gph * E_EDGES, cnt);
        k_blocksum<<<nbScan, 256, 0, stream>>>(cnt, bsum, N_NODES);
        k_scan_bsum<<<1, 512, 0, stream>>>(bsum, bpre, nbScan, row_ptr);
        k_scan_final<<<nbScan, 256, 0, stream>>>(cnt, bpre, row_ptr, fill, N_NODES);
        k_scatter<<<gE, 256, 0, stream>>>(rows + (size_t)gph * E_EDGES,
                                          cols + (size_t)gph * E_EDGES,
                                          vals + (size_t)gph * E_EDGES,
                                          fill, scol, sval);
    };

    // layer 1
    k_gemm_nc128<<<gGemm, 256, 0, stream>>>(x, W1, HA, N_NODES, NFEAT);
    build_csr(0);
    k_spmm_ln_relu<<<gRow, 256, 0, stream>>>(HA, row_ptr, scol, sval, b1, ln_g, ln_b, HB);
    // layer 2
    k_gemm_nc128<<<gGemm, 256, 0, stream>>>(HB, W2, HA, N_NODES, NHID);
    build_csr(1);
    k_spmm_ln_relu<<<gRow, 256, 0, stream>>>(HA, row_ptr, scol, sval, b2, ln_g, ln_b, HB);
    // layer 3
    k_gemm_nc128<<<gGemm, 256, 0, stream>>>(HB, W3, HA, N_NODES, NHID);
    build_csr(2);
    k_spmm_ln_relu<<<gRow, 256, 0, stream>>>(HA, row_ptr, scol, sval, b3, ln_g, ln_b, HB);
    // output
    k_out<<<gRow, 256, 0, stream>>>(HB, Wout, bout, out);
}

// Round 2
// 1126.220 us; speedup vs baseline: 1.1598x; 1.1598x over previous
//
#include <hip/hip_runtime.h>
#include <cstddef>

#define N_NODES 100000
#define E_EDGES 1600000
#define NFEAT   602
#define NHID    128
#define NCLASS  41
#define LN_EPS  1e-5f

typedef __bf16 bf16x8 __attribute__((ext_vector_type(8)));
typedef float f32x4 __attribute__((ext_vector_type(4)));
typedef unsigned short ushort8 __attribute__((ext_vector_type(8)));

__device__ inline unsigned short f2bf(float f) {
    unsigned int u = __builtin_bit_cast(unsigned int, f);
    u += 0x7FFFu + ((u >> 16) & 1u);   // round-to-nearest-even
    return (unsigned short)(u >> 16);
}

// ---------------------------------------------------------------------------
// bf16 MFMA GEMM: C[M x 128] = A[M x K] @ W[K x 128], fp32 in/out,
// on-the-fly bf16 conversion. Tile 128x128, BK=32, 4 waves (2x2), each wave
// 64x64 = 4x4 fragments of 16x16x32.
// LDS: As[row][k], Bs[col][k] (W transposed), rows padded to 40 (80B) to
// break bank-conflict stride.
// ---------------------------------------------------------------------------
#define LDK 40

__global__ __launch_bounds__(256) void k_gemm_mfma(
    const float* __restrict__ A, const float* __restrict__ W,
    float* __restrict__ C, int M, int K)
{
    __shared__ unsigned short As[128][LDK];
    __shared__ unsigned short Bs[128][LDK];

    const int tid = threadIdx.x;
    const int rowBase = blockIdx.x * 128;
    const int wave = tid >> 6, lane = tid & 63;
    const int wm = wave >> 1, wn = wave & 1;
    const int r0 = wm * 64, c0 = wn * 64;
    const int fr = lane & 15, kh = lane >> 4;

    // A-staging indices: thread -> (row, 16-wide k chunk)
    const int arow = tid >> 1;
    const int akq = (tid & 1) * 16;
    // B-staging indices: thread -> (k, 16-wide col chunk)
    const int bk = tid >> 3;
    const int bc = (tid & 7) * 16;

    f32x4 acc[4][4];
#pragma unroll
    for (int m = 0; m < 4; ++m)
#pragma unroll
        for (int n = 0; n < 4; ++n) acc[m][n] = (f32x4)(0.f);

    const int nt = (K + 31) / 32;
    for (int t = 0; t < nt; ++t) {
        const int k0 = t * 32;
        const bool full = (k0 + 32 <= K);

        // ---- stage A tile: 128 rows x 32 k, fp32 -> bf16 ----
        {
            const int grow = rowBase + arow;
            unsigned short tmp[16];
            if (grow < M && full) {
                const float* ap = A + (size_t)grow * K + k0 + akq;
#pragma unroll
                for (int j = 0; j < 8; ++j) {
                    float2 v = *reinterpret_cast<const float2*>(ap + 2 * j);
                    tmp[2 * j]     = f2bf(v.x);
                    tmp[2 * j + 1] = f2bf(v.y);
                }
            } else {
#pragma unroll
                for (int j = 0; j < 16; ++j) {
                    int k = k0 + akq + j;
                    float v = (grow < M && k < K) ? A[(size_t)grow * K + k] : 0.f;
                    tmp[j] = f2bf(v);
                }
            }
            ushort8 lo, hi;
#pragma unroll
            for (int j = 0; j < 8; ++j) { lo[j] = tmp[j]; hi[j] = tmp[8 + j]; }
            *reinterpret_cast<ushort8*>(&As[arow][akq])     = lo;
            *reinterpret_cast<ushort8*>(&As[arow][akq + 8]) = hi;
        }
        // ---- stage B tile transposed: Bs[col][k], 32 k x 128 cols ----
        {
            const int gk = k0 + bk;
            if (gk < K) {
#pragma unroll
                for (int q = 0; q < 4; ++q) {
                    float4 v = *reinterpret_cast<const float4*>(
                        W + (size_t)gk * 128 + bc + 4 * q);
                    Bs[bc + 4 * q + 0][bk] = f2bf(v.x);
                    Bs[bc + 4 * q + 1][bk] = f2bf(v.y);
                    Bs[bc + 4 * q + 2][bk] = f2bf(v.z);
                    Bs[bc + 4 * q + 3][bk] = f2bf(v.w);
                }
            } else {
#pragma unroll
                for (int q = 0; q < 16; ++q) Bs[bc + q][bk] = 0;
            }
        }
        __syncthreads();

        // ---- fragments + MFMA ----
        bf16x8 af[4], bfr[4];
#pragma unroll
        for (int m = 0; m < 4; ++m)
            af[m] = *reinterpret_cast<const bf16x8*>(&As[r0 + m * 16 + fr][kh * 8]);
#pragma unroll
        for (int n = 0; n < 4; ++n)
            bfr[n] = *reinterpret_cast<const bf16x8*>(&Bs[c0 + n * 16 + fr][kh * 8]);
#pragma unroll
        for (int m = 0; m < 4; ++m)
#pragma unroll
            for (int n = 0; n < 4; ++n)
                acc[m][n] = __builtin_amdgcn_mfma_f32_16x16x32_bf16(
                    af[m], bfr[n], acc[m][n], 0, 0, 0);
        __syncthreads();
    }

    // ---- store: row = r0+m*16+kh*4+j, col = c0+n*16+fr ----
#pragma unroll
    for (int m = 0; m < 4; ++m) {
#pragma unroll
        for (int j = 0; j < 4; ++j) {
            int rr = rowBase + r0 + m * 16 + kh * 4 + j;
            if (rr < M) {
#pragma unroll
                for (int n = 0; n < 4; ++n)
                    C[(size_t)rr * 128 + c0 + n * 16 + fr] = acc[m][n][j];
            }
        }
    }
}

// ---------------------------------------------------------------------------
// CSR build: zero, histogram, 3-kernel scan, scatter
// ---------------------------------------------------------------------------
__global__ void k_zero(int* __restrict__ p, int n)
{
    int i = blockIdx.x * blockDim.x + threadIdx.x;
    if (i < n) p[i] = 0;
}

__global__ void k_hist(const int* __restrict__ rows, int* __restrict__ cnt)
{
    int i = blockIdx.x * blockDim.x + threadIdx.x;
    if (i < E_EDGES) atomicAdd(&cnt[rows[i]], 1);
}

__global__ __launch_bounds__(256) void k_blocksum(
    const int* __restrict__ cnt, int* __restrict__ bsum, int n)
{
    __shared__ int sd[256];
    int i = blockIdx.x * 256 + threadIdx.x;
    int v = (i < n) ? cnt[i] : 0;
    sd[threadIdx.x] = v;
    __syncthreads();
    for (int s = 128; s > 0; s >>= 1) {
        if (threadIdx.x < s) sd[threadIdx.x] += sd[threadIdx.x + s];
        __syncthreads();
    }
    if (threadIdx.x == 0) bsum[blockIdx.x] = sd[0];
}

__global__ __launch_bounds__(512) void k_scan_bsum(
    const int* __restrict__ bsum, int* __restrict__ bpre, int nb,
    int* __restrict__ row_ptr)
{
    __shared__ int s[512];
    int t = threadIdx.x;
    int v = (t < nb) ? bsum[t] : 0;
    s[t] = v;
    __syncthreads();
    for (int off = 1; off < 512; off <<= 1) {
        int u = (t >= off) ? s[t - off] : 0;
        __syncthreads();
        s[t] += u;
        __syncthreads();
    }
    if (t < nb) bpre[t] = s[t] - v;   // exclusive
    if (t == 0) row_ptr[N_NODES] = E_EDGES;
}

__global__ __launch_bounds__(256) void k_scan_final(
    const int* __restrict__ cnt, const int* __restrict__ bpre,
    int* __restrict__ row_ptr, int* __restrict__ fill, int n)
{
    __shared__ int s[256];
    int i = blockIdx.x * 256 + threadIdx.x;
    int t = threadIdx.x;
    int v = (i < n) ? cnt[i] : 0;
    s[t] = v;
    __syncthreads();
    for (int off = 1; off < 256; off <<= 1) {
        int u = (t >= off) ? s[t - off] : 0;
        __syncthreads();
        s[t] += u;
        __syncthreads();
    }
    if (i < n) {
        int ex = bpre[blockIdx.x] + s[t] - v;
        row_ptr[i] = ex;
        fill[i] = ex;
    }
}

__global__ void k_scatter(const int* __restrict__ rows, const int* __restrict__ cols,
                          const float* __restrict__ vals, int* __restrict__ fill,
                          int* __restrict__ scol, float* __restrict__ sval)
{
    int i = blockIdx.x * blockDim.x + threadIdx.x;
    if (i < E_EDGES) {
        int r = rows[i];
        int p = atomicAdd(&fill[r], 1);
        scol[p] = cols[i];
        sval[p] = vals[i];
    }
}

// ---------------------------------------------------------------------------
// Fused spmm (CSR gather) + bias + LayerNorm + ReLU.
// One wave (64 lanes) per row; lane handles feats lane and lane+64.
// ---------------------------------------------------------------------------
__global__ __launch_bounds__(256) void k_spmm_ln_relu(
    const float* __restrict__ Hin, const int* __restrict__ row_ptr,
    const int* __restrict__ scol, const float* __restrict__ sval,
    const float* __restrict__ bias, const float* __restrict__ g,
    const float* __restrict__ bb, float* __restrict__ Hout)
{
    const int w = threadIdx.x >> 6;
    const int lane = threadIdx.x & 63;
    const int row = blockIdx.x * 4 + w;
    const int start = row_ptr[row];
    const int end = row_ptr[row + 1];

    float a0 = 0.f, a1 = 0.f;
    int p = start;
    for (; p + 3 < end; p += 4) {
        int c0 = scol[p], c1 = scol[p + 1], c2 = scol[p + 2], c3 = scol[p + 3];
        float v0 = sval[p], v1 = sval[p + 1], v2 = sval[p + 2], v3 = sval[p + 3];
        const float* h0 = Hin + (size_t)c0 * NHID;
        const float* h1 = Hin + (size_t)c1 * NHID;
        const float* h2 = Hin + (size_t)c2 * NHID;
        const float* h3 = Hin + (size_t)c3 * NHID;
        a0 += v0 * h0[lane];      a1 += v0 * h0[64 + lane];
        a0 += v1 * h1[lane];      a1 += v1 * h1[64 + lane];
        a0 += v2 * h2[lane];      a1 += v2 * h2[64 + lane];
        a0 += v3 * h3[lane];      a1 += v3 * h3[64 + lane];
    }
    for (; p < end; ++p) {
        int c = scol[p];
        float v = sval[p];
        a0 += v * Hin[(size_t)c * NHID + lane];
        a1 += v * Hin[(size_t)c * NHID + 64 + lane];
    }
    a0 += bias[lane];
    a1 += bias[64 + lane];

    // LayerNorm over 128 feats (2 per lane, 64-lane wave reduce)
    float sum = a0 + a1, sq = a0 * a0 + a1 * a1;
#pragma unroll
    for (int off = 32; off; off >>= 1) {
        sum += __shfl_xor(sum, off);
        sq  += __shfl_xor(sq, off);
    }
    float mu = sum * (1.f / 128.f);
    float var = sq * (1.f / 128.f) - mu * mu;
    float rs = rsqrtf(var + LN_EPS);
    float y0 = (a0 - mu) * rs * g[lane] + bb[lane];
    float y1 = (a1 - mu) * rs * g[64 + lane] + bb[64 + lane];
    Hout[(size_t)row * NHID + lane]      = fmaxf(y0, 0.f);
    Hout[(size_t)row * NHID + 64 + lane] = fmaxf(y1, 0.f);
}

// ---------------------------------------------------------------------------
// Output: logits = H @ Wout + bout, then log_softmax. One wave per row.
// ---------------------------------------------------------------------------
__global__ __launch_bounds__(256) void k_out(
    const float* __restrict__ H, const float* __restrict__ Wout,
    const float* __restrict__ bout, float* __restrict__ out)
{
    __shared__ float ws[NHID * NCLASS];   // 128*41
    __shared__ float bs[NCLASS];
    __shared__ float hrow[4][NHID];
    for (int i = threadIdx.x; i < NHID * NCLASS; i += 256) ws[i] = Wout[i];
    if (threadIdx.x < NCLASS) bs[threadIdx.x] = bout[threadIdx.x];

    const int w = threadIdx.x >> 6;
    const int lane = threadIdx.x & 63;
    const int row = blockIdx.x * 4 + w;
    hrow[w][lane]      = H[(size_t)row * NHID + lane];
    hrow[w][64 + lane] = H[(size_t)row * NHID + 64 + lane];
    __syncthreads();

    float acc = (lane < NCLASS) ? bs[lane] : 0.f;
    if (lane < NCLASS) {
#pragma unroll 8
        for (int k = 0; k < NHID; ++k) acc += hrow[w][k] * ws[k * NCLASS + lane];
    }
    float x = (lane < NCLASS) ? acc : -1e30f;
    float m = x;
#pragma unroll
    for (int off = 32; off; off >>= 1) m = fmaxf(m, __shfl_xor(m, off));
    float e = (lane < NCLASS) ? expf(x - m) : 0.f;
    float se = e;
#pragma unroll
    for (int off = 32; off; off >>= 1) se += __shfl_xor(se, off);
    if (lane < NCLASS) out[(size_t)row * NCLASS + lane] = x - m - logf(se);
}

// ---------------------------------------------------------------------------
extern "C" void kernel_launch(void* const* d_in, const int* in_sizes, int n_in,
                              void* d_out, int out_size, void* d_ws, size_t ws_size,
                              hipStream_t stream)
{
    const float* x    = (const float*)d_in[0];
    const int*   rows = (const int*)  d_in[1];
    const int*   cols = (const int*)  d_in[2];
    const float* vals = (const float*)d_in[3];
    const float* W1   = (const float*)d_in[4];
    const float* b1   = (const float*)d_in[5];
    const float* W2   = (const float*)d_in[6];
    const float* b2   = (const float*)d_in[7];
    const float* W3   = (const float*)d_in[8];
    const float* b3   = (const float*)d_in[9];
    const float* ln_g = (const float*)d_in[10];
    const float* ln_b = (const float*)d_in[11];
    const float* Wout = (const float*)d_in[12];
    const float* bout = (const float*)d_in[13];
    float* out = (float*)d_out;

    // workspace layout
    float* HA = (float*)d_ws;                               // N*128 f32
    float* HB = HA + (size_t)N_NODES * NHID;                // N*128 f32
    int* cnt     = (int*)(HB + (size_t)N_NODES * NHID);     // N
    int* row_ptr = cnt + N_NODES;                           // N+1
    int* fill    = row_ptr + N_NODES + 1;                   // N+1
    int* bsum    = fill + N_NODES + 1;                      // 512
    int* bpre    = bsum + 512;                              // 512
    int* scol    = bpre + 512;                              // E
    float* sval  = (float*)(scol + E_EDGES);                // E

    const int nbScan = (N_NODES + 255) / 256;               // 391
    const int gE = (E_EDGES + 255) / 256;                   // 6250
    const int gGemm = (N_NODES + 127) / 128;                // 782
    const int gRow = N_NODES / 4;                           // 25000 (exact)

    auto build_csr = [&](int gph) {
        k_zero<<<nbScan, 256, 0, stream>>>(cnt, N_NODES);
        k_hist<<<gE, 256, 0, stream>>>(rows + (size_t)gph * E_EDGES, cnt);
        k_blocksum<<<nbScan, 256, 0, stream>>>(cnt, bsum, N_NODES);
        k_scan_bsum<<<1, 512, 0, stream>>>(bsum, bpre, nbScan, row_ptr);
        k_scan_final<<<nbScan, 256, 0, stream>>>(cnt, bpre, row_ptr, fill, N_NODES);
        k_scatter<<<gE, 256, 0, stream>>>(rows + (size_t)gph * E_EDGES,
                                          cols + (size_t)gph * E_EDGES,
                                          vals + (size_t)gph * E_EDGES,
                                          fill, scol, sval);
    };

    // layer 1
    k_gemm_mfma<<<gGemm, 256, 0, stream>>>(x, W1, HA, N_NODES, NFEAT);
    build_csr(0);
    k_spmm_ln_relu<<<gRow, 256, 0, stream>>>(HA, row_ptr, scol, sval, b1, ln_g, ln_b, HB);
    // layer 2
    k_gemm_mfma<<<gGemm, 256, 0, stream>>>(HB, W2, HA, N_NODES, NHID);
    build_csr(1);
    k_spmm_ln_relu<<<gRow, 256, 0, stream>>>(HA, row_ptr, scol, sval, b2, ln_g, ln_b, HB);
    // layer 3
    k_gemm_mfma<<<gGemm, 256, 0, stream>>>(HB, W3, HA, N_NODES, NHID);
    build_csr(2);
    k_spmm_ln_relu<<<gRow, 256, 0, stream>>>(HA, row_ptr, scol, sval, b3, ln_g, ln_b, HB);
    // output
    k_out<<<gRow, 256, 0, stream>>>(HB, Wout, bout, out);
}

// Round 3
// 1052.111 us; speedup vs baseline: 1.2415x; 1.0704x over previous
//
#include <hip/hip_runtime.h>
#include <cstddef>

#define N_NODES 100000
#define E_EDGES 1600000
#define NFEAT   602
#define NHID    128
#define NCLASS  41
#define LN_EPS  1e-5f

typedef __bf16 bf16x8 __attribute__((ext_vector_type(8)));
typedef float f32x4 __attribute__((ext_vector_type(4)));
typedef unsigned short ushort8 __attribute__((ext_vector_type(8)));

__device__ inline float bf2f(unsigned short u) {
    unsigned int x = (unsigned int)u << 16;
    return __builtin_bit_cast(float, x);
}
__device__ inline unsigned short f2bf(float f) {
    return __builtin_bit_cast(unsigned short, (__bf16)f);
}

// ---------------------------------------------------------------------------
// Pre-swizzle W[K x 128] (fp32) into MFMA B-fragment layout, bf16:
//   Wfrag[((t*8 + n)*64 + lane)*8 + j] = bf16(W[t*32 + (lane>>4)*8 + j][n*16 + (lane&15)])
// zero-padded for k >= K. One wave per (t,n).
// ---------------------------------------------------------------------------
__global__ __launch_bounds__(256) void k_prep_w(
    const float* __restrict__ W, unsigned short* __restrict__ Wfrag,
    int K, int ntile)
{
    const int wid = (blockIdx.x * 256 + threadIdx.x) >> 6;
    const int lane = threadIdx.x & 63;
    const int t = wid >> 3, n = wid & 7;
    if (t >= ntile) return;
    const int fr = lane & 15, kh = lane >> 4;
    const int c = n * 16 + fr;
    ushort8 v;
#pragma unroll
    for (int j = 0; j < 8; ++j) {
        int k = t * 32 + kh * 8 + j;
        float x = (k < K) ? W[(size_t)k * 128 + c] : 0.f;
        v[j] = f2bf(x);
    }
    *reinterpret_cast<ushort8*>(Wfrag + ((size_t)(t * 8 + n) * 64 + lane) * 8) = v;
}

// ---------------------------------------------------------------------------
// Streaming MFMA GEMM, no LDS, no barriers.
// C[M x 128] (bf16) = A[M x K] @ W[K x 128]  (W pre-swizzled in Wfrag).
// Block = 4 waves; each wave owns 32 rows x 128 cols: acc[2][8] fragments.
// A fragments loaded directly from global (contiguous per lane), B fragments
// are coalesced 1KB wave reads from L2-resident Wfrag.
// ---------------------------------------------------------------------------
template<bool BF16A>
__global__ __launch_bounds__(256) void k_gemm_stream(
    const void* __restrict__ Ain, const unsigned short* __restrict__ Wfrag,
    unsigned short* __restrict__ C, int M, int K)
{
    const int lane = threadIdx.x & 63;
    const int wv = threadIdx.x >> 6;
    const int fr = lane & 15, kh = lane >> 4;
    const int row0 = blockIdx.x * 128 + wv * 32;

    f32x4 acc[2][8];
#pragma unroll
    for (int m = 0; m < 2; ++m)
#pragma unroll
        for (int n = 0; n < 8; ++n) acc[m][n] = (f32x4)(0.f);

    const int nt = (K + 31) / 32;
    for (int t = 0; t < nt; ++t) {
        const int k0 = t * 32;
        bf16x8 af[2];
        if (BF16A) {
            const unsigned short* A16 = (const unsigned short*)Ain;
#pragma unroll
            for (int m = 0; m < 2; ++m) {
                int ar = row0 + m * 16 + fr;
                if (ar > M - 1) ar = M - 1;   // clamp: valid data, lands in dead C rows
                af[m] = __builtin_bit_cast(bf16x8,
                    *reinterpret_cast<const ushort8*>(A16 + (size_t)ar * NHID + k0 + kh * 8));
            }
        } else {
            const float* A32 = (const float*)Ain;
            const bool full = (k0 + 32 <= K);
#pragma unroll
            for (int m = 0; m < 2; ++m) {
                int ar = row0 + m * 16 + fr;
                if (ar > M - 1) ar = M - 1;   // clamp
                const float* ap = A32 + (size_t)ar * K + k0 + kh * 8;
                if (full) {
                    float4 v0 = *reinterpret_cast<const float4*>(ap);
                    float4 v1 = *reinterpret_cast<const float4*>(ap + 4);
                    af[m][0] = (__bf16)v0.x; af[m][1] = (__bf16)v0.y;
                    af[m][2] = (__bf16)v0.z; af[m][3] = (__bf16)v0.w;
                    af[m][4] = (__bf16)v1.x; af[m][5] = (__bf16)v1.y;
                    af[m][6] = (__bf16)v1.z; af[m][7] = (__bf16)v1.w;
                } else {
#pragma unroll
                    for (int j = 0; j < 8; ++j) {
                        int k = k0 + kh * 8 + j;
                        float v = (k < K) ? ap[j] : 0.f;
                        af[m][j] = (__bf16)v;
                    }
                }
            }
        }
        const unsigned short* wp = Wfrag + (size_t)t * 4096 + (size_t)lane * 8;
#pragma unroll
        for (int n = 0; n < 8; ++n) {
            bf16x8 bf = __builtin_bit_cast(bf16x8,
                *reinterpret_cast<const ushort8*>(wp + n * 512));
            acc[0][n] = __builtin_amdgcn_mfma_f32_16x16x32_bf16(af[0], bf, acc[0][n], 0, 0, 0);
            acc[1][n] = __builtin_amdgcn_mfma_f32_16x16x32_bf16(af[1], bf, acc[1][n], 0, 0, 0);
        }
    }

    // store: row = row0 + m*16 + kh*4 + jj, col = n*16 + fr
#pragma unroll
    for (int m = 0; m < 2; ++m) {
#pragma unroll
        for (int jj = 0; jj < 4; ++jj) {
            int cr = row0 + m * 16 + kh * 4 + jj;
            if (cr < M) {
#pragma unroll
                for (int n = 0; n < 8; ++n)
                    C[(size_t)cr * NHID + n * 16 + fr] = f2bf(acc[m][n][jj]);
            }
        }
    }
}

// ---------------------------------------------------------------------------
// CSR build: zero, histogram, 3-kernel scan, scatter
// ---------------------------------------------------------------------------
__global__ void k_zero(int* __restrict__ p, int n)
{
    int i = blockIdx.x * blockDim.x + threadIdx.x;
    if (i < n) p[i] = 0;
}

__global__ void k_hist(const int* __restrict__ rows, int* __restrict__ cnt)
{
    int i = blockIdx.x * blockDim.x + threadIdx.x;
    if (i < E_EDGES) atomicAdd(&cnt[rows[i]], 1);
}

__global__ __launch_bounds__(256) void k_blocksum(
    const int* __restrict__ cnt, int* __restrict__ bsum, int n)
{
    __shared__ int sd[256];
    int i = blockIdx.x * 256 + threadIdx.x;
    int v = (i < n) ? cnt[i] : 0;
    sd[threadIdx.x] = v;
    __syncthreads();
    for (int s = 128; s > 0; s >>= 1) {
        if (threadIdx.x < s) sd[threadIdx.x] += sd[threadIdx.x + s];
        __syncthreads();
    }
    if (threadIdx.x == 0) bsum[blockIdx.x] = sd[0];
}

__global__ __launch_bounds__(512) void k_scan_bsum(
    const int* __restrict__ bsum, int* __restrict__ bpre, int nb,
    int* __restrict__ row_ptr)
{
    __shared__ int s[512];
    int t = threadIdx.x;
    int v = (t < nb) ? bsum[t] : 0;
    s[t] = v;
    __syncthreads();
    for (int off = 1; off < 512; off <<= 1) {
        int u = (t >= off) ? s[t - off] : 0;
        __syncthreads();
        s[t] += u;
        __syncthreads();
    }
    if (t < nb) bpre[t] = s[t] - v;   // exclusive
    if (t == 0) row_ptr[N_NODES] = E_EDGES;
}

__global__ __launch_bounds__(256) void k_scan_final(
    const int* __restrict__ cnt, const int* __restrict__ bpre,
    int* __restrict__ row_ptr, int* __restrict__ fill, int n)
{
    __shared__ int s[256];
    int i = blockIdx.x * 256 + threadIdx.x;
    int t = threadIdx.x;
    int v = (i < n) ? cnt[i] : 0;
    s[t] = v;
    __syncthreads();
    for (int off = 1; off < 256; off <<= 1) {
        int u = (t >= off) ? s[t - off] : 0;
        __syncthreads();
        s[t] += u;
        __syncthreads();
    }
    if (i < n) {
        int ex = bpre[blockIdx.x] + s[t] - v;
        row_ptr[i] = ex;
        fill[i] = ex;
    }
}

__global__ void k_scatter(const int* __restrict__ rows, const int* __restrict__ cols,
                          const float* __restrict__ vals, int* __restrict__ fill,
                          int* __restrict__ scol, float* __restrict__ sval)
{
    int i = blockIdx.x * blockDim.x + threadIdx.x;
    if (i < E_EDGES) {
        int r = rows[i];
        int p = atomicAdd(&fill[r], 1);
        scol[p] = cols[i];
        sval[p] = vals[i];
    }
}

// ---------------------------------------------------------------------------
// Fused spmm (CSR gather, bf16 H) + bias + LayerNorm + ReLU -> bf16 out.
// One wave per row; lane handles feats lane and lane+64.
// ---------------------------------------------------------------------------
__global__ __launch_bounds__(256) void k_spmm_ln_relu(
    const unsigned short* __restrict__ Hin, const int* __restrict__ row_ptr,
    const int* __restrict__ scol, const float* __restrict__ sval,
    const float* __restrict__ bias, const float* __restrict__ g,
    const float* __restrict__ bb, unsigned short* __restrict__ Hout)
{
    const int w = threadIdx.x >> 6;
    const int lane = threadIdx.x & 63;
    const int row = blockIdx.x * 4 + w;
    const int start = row_ptr[row];
    const int end = row_ptr[row + 1];

    float a0 = 0.f, a1 = 0.f;
    int p = start;
    for (; p + 3 < end; p += 4) {
        int c0 = scol[p], c1 = scol[p + 1], c2 = scol[p + 2], c3 = scol[p + 3];
        float v0 = sval[p], v1 = sval[p + 1], v2 = sval[p + 2], v3 = sval[p + 3];
        const unsigned short* h0 = Hin + (size_t)c0 * NHID;
        const unsigned short* h1 = Hin + (size_t)c1 * NHID;
        const unsigned short* h2 = Hin + (size_t)c2 * NHID;
        const unsigned short* h3 = Hin + (size_t)c3 * NHID;
        a0 += v0 * bf2f(h0[lane]);      a1 += v0 * bf2f(h0[64 + lane]);
        a0 += v1 * bf2f(h1[lane]);      a1 += v1 * bf2f(h1[64 + lane]);
        a0 += v2 * bf2f(h2[lane]);      a1 += v2 * bf2f(h2[64 + lane]);
        a0 += v3 * bf2f(h3[lane]);      a1 += v3 * bf2f(h3[64 + lane]);
    }
    for (; p < end; ++p) {
        int c = scol[p];
        float v = sval[p];
        a0 += v * bf2f(Hin[(size_t)c * NHID + lane]);
        a1 += v * bf2f(Hin[(size_t)c * NHID + 64 + lane]);
    }
    a0 += bias[lane];
    a1 += bias[64 + lane];

    float sum = a0 + a1, sq = a0 * a0 + a1 * a1;
#pragma unroll
    for (int off = 32; off; off >>= 1) {
        sum += __shfl_xor(sum, off);
        sq  += __shfl_xor(sq, off);
    }
    float mu = sum * (1.f / 128.f);
    float var = sq * (1.f / 128.f) - mu * mu;
    float rs = rsqrtf(var + LN_EPS);
    float y0 = (a0 - mu) * rs * g[lane] + bb[lane];
    float y1 = (a1 - mu) * rs * g[64 + lane] + bb[64 + lane];
    Hout[(size_t)row * NHID + lane]      = f2bf(fmaxf(y0, 0.f));
    Hout[(size_t)row * NHID + 64 + lane] = f2bf(fmaxf(y1, 0.f));
}

// ---------------------------------------------------------------------------
// Output: logits = H @ Wout + bout, then log_softmax. One wave per row.
// ---------------------------------------------------------------------------
__global__ __launch_bounds__(256) void k_out(
    const unsigned short* __restrict__ H, const float* __restrict__ Wout,
    const float* __restrict__ bout, float* __restrict__ out)
{
    __shared__ float ws[NHID * NCLASS];
    __shared__ float bs[NCLASS];
    __shared__ float hrow[4][NHID];
    for (int i = threadIdx.x; i < NHID * NCLASS; i += 256) ws[i] = Wout[i];
    if (threadIdx.x < NCLASS) bs[threadIdx.x] = bout[threadIdx.x];

    const int w = threadIdx.x >> 6;
    const int lane = threadIdx.x & 63;
    const int row = blockIdx.x * 4 + w;
    hrow[w][lane]      = bf2f(H[(size_t)row * NHID + lane]);
    hrow[w][64 + lane] = bf2f(H[(size_t)row * NHID + 64 + lane]);
    __syncthreads();

    float acc = (lane < NCLASS) ? bs[lane] : 0.f;
    if (lane < NCLASS) {
#pragma unroll 8
        for (int k = 0; k < NHID; ++k) acc += hrow[w][k] * ws[k * NCLASS + lane];
    }
    float x = (lane < NCLASS) ? acc : -1e30f;
    float m = x;
#pragma unroll
    for (int off = 32; off; off >>= 1) m = fmaxf(m, __shfl_xor(m, off));
    float e = (lane < NCLASS) ? expf(x - m) : 0.f;
    float se = e;
#pragma unroll
    for (int off = 32; off; off >>= 1) se += __shfl_xor(se, off);
    if (lane < NCLASS) out[(size_t)row * NCLASS + lane] = x - m - logf(se);
}

// ---------------------------------------------------------------------------
extern "C" void kernel_launch(void* const* d_in, const int* in_sizes, int n_in,
                              void* d_out, int out_size, void* d_ws, size_t ws_size,
                              hipStream_t stream)
{
    const float* x    = (const float*)d_in[0];
    const int*   rows = (const int*)  d_in[1];
    const int*   cols = (const int*)  d_in[2];
    const float* vals = (const float*)d_in[3];
    const float* W1   = (const float*)d_in[4];
    const float* b1   = (const float*)d_in[5];
    const float* W2   = (const float*)d_in[6];
    const float* b2   = (const float*)d_in[7];
    const float* W3   = (const float*)d_in[8];
    const float* b3   = (const float*)d_in[9];
    const float* ln_g = (const float*)d_in[10];
    const float* ln_b = (const float*)d_in[11];
    const float* Wout = (const float*)d_in[12];
    const float* bout = (const float*)d_in[13];
    float* out = (float*)d_out;

    const int NT1 = (NFEAT + 31) / 32;   // 19
    const int NT2 = (NHID + 31) / 32;    // 4

    // workspace layout (all 16B-aligned)
    unsigned short* HA16 = (unsigned short*)d_ws;                 // N*128 bf16
    unsigned short* HB16 = HA16 + (size_t)N_NODES * NHID;         // N*128 bf16
    unsigned short* Wf1  = HB16 + (size_t)N_NODES * NHID;         // NT1*8*64*8
    unsigned short* Wf2  = Wf1 + (size_t)NT1 * 4096;              // NT2*8*64*8
    unsigned short* Wf3  = Wf2 + (size_t)NT2 * 4096;
    int* cnt     = (int*)(Wf3 + (size_t)NT2 * 4096);              // N
    int* row_ptr = cnt + N_NODES;                                 // N+1
    int* fill    = row_ptr + N_NODES + 1;                         // N+1
    int* bsum    = fill + N_NODES + 1;                            // 512
    int* bpre    = bsum + 512;                                    // 512
    int* scol    = bpre + 512;                                    // E
    float* sval  = (float*)(scol + E_EDGES);                      // E

    const int nbScan = (N_NODES + 255) / 256;               // 391
    const int gE = (E_EDGES + 255) / 256;                   // 6250
    const int gGemm = (N_NODES + 127) / 128;                // 782
    const int gRow = N_NODES / 4;                           // 25000 (exact)

    auto build_csr = [&](int gph) {
        k_zero<<<nbScan, 256, 0, stream>>>(cnt, N_NODES);
        k_hist<<<gE, 256, 0, stream>>>(rows + (size_t)gph * E_EDGES, cnt);
        k_blocksum<<<nbScan, 256, 0, stream>>>(cnt, bsum, N_NODES);
        k_scan_bsum<<<1, 512, 0, stream>>>(bsum, bpre, nbScan, row_ptr);
        k_scan_final<<<nbScan, 256, 0, stream>>>(cnt, bpre, row_ptr, fill, N_NODES);
        k_scatter<<<gE, 256, 0, stream>>>(rows + (size_t)gph * E_EDGES,
                                          cols + (size_t)gph * E_EDGES,
                                          vals + (size_t)gph * E_EDGES,
                                          fill, scol, sval);
    };

    // weight pre-swizzle (tiny)
    k_prep_w<<<(NT1 * 8 + 3) / 4, 256, 0, stream>>>(W1, Wf1, NFEAT, NT1);
    k_prep_w<<<(NT2 * 8 + 3) / 4, 256, 0, stream>>>(W2, Wf2, NHID, NT2);
    k_prep_w<<<(NT2 * 8 + 3) / 4, 256, 0, stream>>>(W3, Wf3, NHID, NT2);

    // layer 1
    k_gemm_stream<false><<<gGemm, 256, 0, stream>>>(x, Wf1, HA16, N_NODES, NFEAT);
    build_csr(0);
    k_spmm_ln_relu<<<gRow, 256, 0, stream>>>(HA16, row_ptr, scol, sval, b1, ln_g, ln_b, HB16);
    // layer 2
    k_gemm_stream<true><<<gGemm, 256, 0, stream>>>(HB16, Wf2, HA16, N_NODES, NHID);
    build_csr(1);
    k_spmm_ln_relu<<<gRow, 256, 0, stream>>>(HA16, row_ptr, scol, sval, b2, ln_g, ln_b, HB16);
    // layer 3
    k_gemm_stream<true><<<gGemm, 256, 0, stream>>>(HB16, Wf3, HA16, N_NODES, NHID);
    build_csr(2);
    k_spmm_ln_relu<<<gRow, 256, 0, stream>>>(HA16, row_ptr, scol, sval, b3, ln_g, ln_b, HB16);
    // output
    k_out<<<gRow, 256, 0, stream>>>(HB16, Wout, bout, out);
}

// Round 4
// 1006.418 us; speedup vs baseline: 1.2978x; 1.0454x over previous
//
#include <hip/hip_runtime.h>
#include <cstddef>

#define N_NODES 100000
#define E_EDGES 1600000
#define NFEAT   602
#define NHID    128
#define NCLASS  41
#define LN_EPS  1e-5f

typedef __bf16 bf16x8 __attribute__((ext_vector_type(8)));
typedef float f32x4 __attribute__((ext_vector_type(4)));
typedef unsigned short ushort8 __attribute__((ext_vector_type(8)));

__device__ inline float bf2f(unsigned short u) {
    unsigned int x = (unsigned int)u << 16;
    return __builtin_bit_cast(float, x);
}
__device__ inline unsigned short f2bf(float f) {
    return __builtin_bit_cast(unsigned short, (__bf16)f);
}

// ---------------------------------------------------------------------------
// Pre-swizzle W[K x 128] (fp32) into MFMA B-fragment layout, bf16:
//   Wfrag[((t*8 + n)*64 + lane)*8 + j] = bf16(W[t*32 + (lane>>4)*8 + j][n*16 + (lane&15)])
// zero-padded for k >= K. One wave per (t,n).
// ---------------------------------------------------------------------------
__global__ __launch_bounds__(256) void k_prep_w(
    const float* __restrict__ W, unsigned short* __restrict__ Wfrag,
    int K, int ntile)
{
    const int wid = (blockIdx.x * 256 + threadIdx.x) >> 6;
    const int lane = threadIdx.x & 63;
    const int t = wid >> 3, n = wid & 7;
    if (t >= ntile) return;
    const int fr = lane & 15, kh = lane >> 4;
    const int c = n * 16 + fr;
    ushort8 v;
#pragma unroll
    for (int j = 0; j < 8; ++j) {
        int k = t * 32 + kh * 8 + j;
        float x = (k < K) ? W[(size_t)k * 128 + c] : 0.f;
        v[j] = f2bf(x);
    }
    *reinterpret_cast<ushort8*>(Wfrag + ((size_t)(t * 8 + n) * 64 + lane) * 8) = v;
}

// ---------------------------------------------------------------------------
// Slab GEMM: C[M x 128] (bf16) = A[M x K] @ W (pre-swizzled Wfrag, bf16).
// Block = 512 threads, 64 rows of A. The 64-row slab is CONTIGUOUS in memory:
// staged flat into LDS (fp32->bf16 on the fly) with perfectly coalesced
// float4 loads. 8 waves each compute 16 rows x 64 cols (acc[1][4]).
// LDS row stride KPAD (mult of 8 shorts): 16B-aligned ds_read_b128, and
// stride mod 32 dwords = 20 (K=602) / 4 (K=128) -> <=2-way bank aliasing.
// ---------------------------------------------------------------------------
template<int KK, bool BF16A>
__global__ __launch_bounds__(512) void k_gemm_slab(
    const void* __restrict__ Ain, const unsigned short* __restrict__ Wfrag,
    unsigned short* __restrict__ C, int M)
{
    constexpr int NT = (KK + 31) / 32;
    constexpr int KPAD = ((KK + 7) / 8) * 8 + 8;   // 602->616, 128->136
    __shared__ unsigned short As[64 * KPAD + 8];

    const int tid = threadIdx.x;
    const int row0 = blockIdx.x * 64;
    const int nrow = (M - row0 < 64) ? (M - row0) : 64;
    const int total = nrow * KK;

    // ---- stage slab ----
    if (!BF16A) {
        const float* A32 = (const float*)Ain + (size_t)row0 * KK;
        constexpr int totalFull = 64 * KK;
#pragma unroll 4
        for (int base = 0; base < totalFull; base += 2048) {
            int i = base + tid * 4;
            if (i < totalFull) {
                float4 v = make_float4(0.f, 0.f, 0.f, 0.f);
                if (i + 4 <= total) {
                    v = *reinterpret_cast<const float4*>(A32 + i);
                } else if (i < total) {
                    float tmp[4] = {0.f, 0.f, 0.f, 0.f};
#pragma unroll
                    for (int e = 0; e < 4; ++e) if (i + e < total) tmp[e] = A32[i + e];
                    v = make_float4(tmp[0], tmp[1], tmp[2], tmp[3]);
                }
                int row = i / KK;
                int col = i - row * KK;          // always even (KK even, i mult 4)
                unsigned int d0 = (unsigned int)f2bf(v.x) | ((unsigned int)f2bf(v.y) << 16);
                unsigned int d1 = (unsigned int)f2bf(v.z) | ((unsigned int)f2bf(v.w) << 16);
                int a0 = row * KPAD + col;
                int a1 = (col == KK - 2) ? (row + 1) * KPAD : a0 + 2;
                *reinterpret_cast<unsigned int*>(&As[a0]) = d0;
                *reinterpret_cast<unsigned int*>(&As[a1]) = d1;
            }
        }
    } else {
        const unsigned short* A16 = (const unsigned short*)Ain + (size_t)row0 * KK;
        constexpr int totalFull = 64 * KK;
#pragma unroll
        for (int base = 0; base < totalFull; base += 4096) {
            int i = base + tid * 8;
            if (i < totalFull) {
                ushort8 v;
#pragma unroll
                for (int j = 0; j < 8; ++j) v[j] = 0;
                if (i + 8 <= total) v = *reinterpret_cast<const ushort8*>(A16 + i);
                int row = i / KK;
                int col = i - row * KK;          // mult of 8
                *reinterpret_cast<ushort8*>(&As[row * KPAD + col]) = v;
            }
        }
    }
    __syncthreads();

    // ---- compute: wave wv -> A-fragment (wv>>1), col half (wv&1) ----
    const int wv = tid >> 6, lane = tid & 63;
    const int fr = lane & 15, kh = lane >> 4;
    const int mfr = wv >> 1;
    const int ch = wv & 1;
    const unsigned short* abase = &As[(mfr * 16 + fr) * KPAD + kh * 8];
    const unsigned short* wbase = Wfrag + ((size_t)(ch * 4) * 64 + lane) * 8;

    f32x4 acc[4];
#pragma unroll
    for (int n = 0; n < 4; ++n) acc[n] = (f32x4)(0.f);

    bf16x8 bcur[4];
#pragma unroll
    for (int n = 0; n < 4; ++n)
        bcur[n] = __builtin_bit_cast(bf16x8,
            *reinterpret_cast<const ushort8*>(wbase + n * 512));

#pragma unroll
    for (int t = 0; t < NT; ++t) {
        bf16x8 bnext[4];
        if (t + 1 < NT) {
            const unsigned short* wp = wbase + (size_t)(t + 1) * 4096;
#pragma unroll
            for (int n = 0; n < 4; ++n)
                bnext[n] = __builtin_bit_cast(bf16x8,
                    *reinterpret_cast<const ushort8*>(wp + n * 512));
        }
        bf16x8 af = *reinterpret_cast<const bf16x8*>(abase + t * 32);
        if (KK % 32 != 0 && t == NT - 1) {
#pragma unroll
            for (int j = 0; j < 8; ++j)
                if (t * 32 + kh * 8 + j >= KK) af[j] = (__bf16)0.f;
        }
#pragma unroll
        for (int n = 0; n < 4; ++n)
            acc[n] = __builtin_amdgcn_mfma_f32_16x16x32_bf16(af, bcur[n], acc[n], 0, 0, 0);
#pragma unroll
        for (int n = 0; n < 4; ++n) bcur[n] = bnext[n];
    }

    // ---- store: row = row0 + mfr*16 + kh*4 + jj, col = ch*64 + n*16 + fr ----
#pragma unroll
    for (int jj = 0; jj < 4; ++jj) {
        int cr = row0 + mfr * 16 + kh * 4 + jj;
        if (cr < M) {
#pragma unroll
            for (int n = 0; n < 4; ++n)
                C[(size_t)cr * NHID + ch * 64 + n * 16 + fr] = f2bf(acc[n][jj]);
        }
    }
}

// ---------------------------------------------------------------------------
// CSR build: zero, histogram, 3-kernel scan, scatter
// ---------------------------------------------------------------------------
__global__ void k_zero(int* __restrict__ p, int n)
{
    int i = blockIdx.x * blockDim.x + threadIdx.x;
    if (i < n) p[i] = 0;
}

__global__ void k_hist(const int* __restrict__ rows, int* __restrict__ cnt)
{
    int i = blockIdx.x * blockDim.x + threadIdx.x;
    if (i < E_EDGES) atomicAdd(&cnt[rows[i]], 1);
}

__global__ __launch_bounds__(256) void k_blocksum(
    const int* __restrict__ cnt, int* __restrict__ bsum, int n)
{
    __shared__ int sd[256];
    int i = blockIdx.x * 256 + threadIdx.x;
    int v = (i < n) ? cnt[i] : 0;
    sd[threadIdx.x] = v;
    __syncthreads();
    for (int s = 128; s > 0; s >>= 1) {
        if (threadIdx.x < s) sd[threadIdx.x] += sd[threadIdx.x + s];
        __syncthreads();
    }
    if (threadIdx.x == 0) bsum[blockIdx.x] = sd[0];
}

__global__ __launch_bounds__(512) void k_scan_bsum(
    const int* __restrict__ bsum, int* __restrict__ bpre, int nb,
    int* __restrict__ row_ptr)
{
    __shared__ int s[512];
    int t = threadIdx.x;
    int v = (t < nb) ? bsum[t] : 0;
    s[t] = v;
    __syncthreads();
    for (int off = 1; off < 512; off <<= 1) {
        int u = (t >= off) ? s[t - off] : 0;
        __syncthreads();
        s[t] += u;
        __syncthreads();
    }
    if (t < nb) bpre[t] = s[t] - v;   // exclusive
    if (t == 0) row_ptr[N_NODES] = E_EDGES;
}

__global__ __launch_bounds__(256) void k_scan_final(
    const int* __restrict__ cnt, const int* __restrict__ bpre,
    int* __restrict__ row_ptr, int* __restrict__ fill, int n)
{
    __shared__ int s[256];
    int i = blockIdx.x * 256 + threadIdx.x;
    int t = threadIdx.x;
    int v = (i < n) ? cnt[i] : 0;
    s[t] = v;
    __syncthreads();
    for (int off = 1; off < 256; off <<= 1) {
        int u = (t >= off) ? s[t - off] : 0;
        __syncthreads();
        s[t] += u;
        __syncthreads();
    }
    if (i < n) {
        int ex = bpre[blockIdx.x] + s[t] - v;
        row_ptr[i] = ex;
        fill[i] = ex;
    }
}

__global__ void k_scatter(const int* __restrict__ rows, const int* __restrict__ cols,
                          const float* __restrict__ vals, int* __restrict__ fill,
                          int* __restrict__ scol, float* __restrict__ sval)
{
    int i = blockIdx.x * blockDim.x + threadIdx.x;
    if (i < E_EDGES) {
        int r = rows[i];
        int p = atomicAdd(&fill[r], 1);
        scol[p] = cols[i];
        sval[p] = vals[i];
    }
}

// ---------------------------------------------------------------------------
// Fused spmm (CSR gather, bf16 H) + bias + LayerNorm + ReLU -> bf16 out.
// One wave per row; lane handles feats lane and lane+64.
// ---------------------------------------------------------------------------
__global__ __launch_bounds__(256) void k_spmm_ln_relu(
    const unsigned short* __restrict__ Hin, const int* __restrict__ row_ptr,
    const int* __restrict__ scol, const float* __restrict__ sval,
    const float* __restrict__ bias, const float* __restrict__ g,
    const float* __restrict__ bb, unsigned short* __restrict__ Hout)
{
    const int w = threadIdx.x >> 6;
    const int lane = threadIdx.x & 63;
    const int row = blockIdx.x * 4 + w;
    const int start = row_ptr[row];
    const int end = row_ptr[row + 1];

    float a0 = 0.f, a1 = 0.f;
    int p = start;
    for (; p + 3 < end; p += 4) {
        int c0 = scol[p], c1 = scol[p + 1], c2 = scol[p + 2], c3 = scol[p + 3];
        float v0 = sval[p], v1 = sval[p + 1], v2 = sval[p + 2], v3 = sval[p + 3];
        const unsigned short* h0 = Hin + (size_t)c0 * NHID;
        const unsigned short* h1 = Hin + (size_t)c1 * NHID;
        const unsigned short* h2 = Hin + (size_t)c2 * NHID;
        const unsigned short* h3 = Hin + (size_t)c3 * NHID;
        a0 += v0 * bf2f(h0[lane]);      a1 += v0 * bf2f(h0[64 + lane]);
        a0 += v1 * bf2f(h1[lane]);      a1 += v1 * bf2f(h1[64 + lane]);
        a0 += v2 * bf2f(h2[lane]);      a1 += v2 * bf2f(h2[64 + lane]);
        a0 += v3 * bf2f(h3[lane]);      a1 += v3 * bf2f(h3[64 + lane]);
    }
    for (; p < end; ++p) {
        int c = scol[p];
        float v = sval[p];
        a0 += v * bf2f(Hin[(size_t)c * NHID + lane]);
        a1 += v * bf2f(Hin[(size_t)c * NHID + 64 + lane]);
    }
    a0 += bias[lane];
    a1 += bias[64 + lane];

    float sum = a0 + a1, sq = a0 * a0 + a1 * a1;
#pragma unroll
    for (int off = 32; off; off >>= 1) {
        sum += __shfl_xor(sum, off);
        sq  += __shfl_xor(sq, off);
    }
    float mu = sum * (1.f / 128.f);
    float var = sq * (1.f / 128.f) - mu * mu;
    float rs = rsqrtf(var + LN_EPS);
    float y0 = (a0 - mu) * rs * g[lane] + bb[lane];
    float y1 = (a1 - mu) * rs * g[64 + lane] + bb[64 + lane];
    Hout[(size_t)row * NHID + lane]      = f2bf(fmaxf(y0, 0.f));
    Hout[(size_t)row * NHID + 64 + lane] = f2bf(fmaxf(y1, 0.f));
}

// ---------------------------------------------------------------------------
// Output: logits = H @ Wout + bout, then log_softmax. One wave per row.
// ---------------------------------------------------------------------------
__global__ __launch_bounds__(256) void k_out(
    const unsigned short* __restrict__ H, const float* __restrict__ Wout,
    const float* __restrict__ bout, float* __restrict__ out)
{
    __shared__ float ws[NHID * NCLASS];
    __shared__ float bs[NCLASS];
    __shared__ float hrow[4][NHID];
    for (int i = threadIdx.x; i < NHID * NCLASS; i += 256) ws[i] = Wout[i];
    if (threadIdx.x < NCLASS) bs[threadIdx.x] = bout[threadIdx.x];

    const int w = threadIdx.x >> 6;
    const int lane = threadIdx.x & 63;
    const int row = blockIdx.x * 4 + w;
    hrow[w][lane]      = bf2f(H[(size_t)row * NHID + lane]);
    hrow[w][64 + lane] = bf2f(H[(size_t)row * NHID + 64 + lane]);
    __syncthreads();

    float acc = (lane < NCLASS) ? bs[lane] : 0.f;
    if (lane < NCLASS) {
#pragma unroll 8
        for (int k = 0; k < NHID; ++k) acc += hrow[w][k] * ws[k * NCLASS + lane];
    }
    float x = (lane < NCLASS) ? acc : -1e30f;
    float m = x;
#pragma unroll
    for (int off = 32; off; off >>= 1) m = fmaxf(m, __shfl_xor(m, off));
    float e = (lane < NCLASS) ? expf(x - m) : 0.f;
    float se = e;
#pragma unroll
    for (int off = 32; off; off >>= 1) se += __shfl_xor(se, off);
    if (lane < NCLASS) out[(size_t)row * NCLASS + lane] = x - m - logf(se);
}

// ---------------------------------------------------------------------------
extern "C" void kernel_launch(void* const* d_in, const int* in_sizes, int n_in,
                              void* d_out, int out_size, void* d_ws, size_t ws_size,
                              hipStream_t stream)
{
    const float* x    = (const float*)d_in[0];
    const int*   rows = (const int*)  d_in[1];
    const int*   cols = (const int*)  d_in[2];
    const float* vals = (const float*)d_in[3];
    const float* W1   = (const float*)d_in[4];
    const float* b1   = (const float*)d_in[5];
    const float* W2   = (const float*)d_in[6];
    const float* b2   = (const float*)d_in[7];
    const float* W3   = (const float*)d_in[8];
    const float* b3   = (const float*)d_in[9];
    const float* ln_g = (const float*)d_in[10];
    const float* ln_b = (const float*)d_in[11];
    const float* Wout = (const float*)d_in[12];
    const float* bout = (const float*)d_in[13];
    float* out = (float*)d_out;

    const int NT1 = (NFEAT + 31) / 32;   // 19
    const int NT2 = (NHID + 31) / 32;    // 4

    // workspace layout (all 16B-aligned)
    unsigned short* HA16 = (unsigned short*)d_ws;                 // N*128 bf16
    unsigned short* HB16 = HA16 + (size_t)N_NODES * NHID;         // N*128 bf16
    unsigned short* Wf1  = HB16 + (size_t)N_NODES * NHID;         // NT1*8*64*8
    unsigned short* Wf2  = Wf1 + (size_t)NT1 * 4096;              // NT2*8*64*8
    unsigned short* Wf3  = Wf2 + (size_t)NT2 * 4096;
    int* cnt     = (int*)(Wf3 + (size_t)NT2 * 4096);              // N
    int* row_ptr = cnt + N_NODES;                                 // N+1
    int* fill    = row_ptr + N_NODES + 1;                         // N+1
    int* bsum    = fill + N_NODES + 1;                            // 512
    int* bpre    = bsum + 512;                                    // 512
    int* scol    = bpre + 512;                                    // E
    float* sval  = (float*)(scol + E_EDGES);                      // E

    const int nbScan = (N_NODES + 255) / 256;               // 391
    const int gE = (E_EDGES + 255) / 256;                   // 6250
    const int gGemm = (N_NODES + 63) / 64;                  // 1563
    const int gRow = N_NODES / 4;                           // 25000 (exact)

    auto build_csr = [&](int gph) {
        k_zero<<<nbScan, 256, 0, stream>>>(cnt, N_NODES);
        k_hist<<<gE, 256, 0, stream>>>(rows + (size_t)gph * E_EDGES, cnt);
        k_blocksum<<<nbScan, 256, 0, stream>>>(cnt, bsum, N_NODES);
        k_scan_bsum<<<1, 512, 0, stream>>>(bsum, bpre, nbScan, row_ptr);
        k_scan_final<<<nbScan, 256, 0, stream>>>(cnt, bpre, row_ptr, fill, N_NODES);
        k_scatter<<<gE, 256, 0, stream>>>(rows + (size_t)gph * E_EDGES,
                                          cols + (size_t)gph * E_EDGES,
                                          vals + (size_t)gph * E_EDGES,
                                          fill, scol, sval);
    };

    // weight pre-swizzle (tiny)
    k_prep_w<<<(NT1 * 8 + 3) / 4, 256, 0, stream>>>(W1, Wf1, NFEAT, NT1);
    k_prep_w<<<(NT2 * 8 + 3) / 4, 256, 0, stream>>>(W2, Wf2, NHID, NT2);
    k_prep_w<<<(NT2 * 8 + 3) / 4, 256, 0, stream>>>(W3, Wf3, NHID, NT2);

    // layer 1
    k_gemm_slab<NFEAT, false><<<gGemm, 512, 0, stream>>>(x, Wf1, HA16, N_NODES);
    build_csr(0);
    k_spmm_ln_relu<<<gRow, 256, 0, stream>>>(HA16, row_ptr, scol, sval, b1, ln_g, ln_b, HB16);
    // layer 2
    k_gemm_slab<NHID, true><<<gGemm, 512, 0, stream>>>(HB16, Wf2, HA16, N_NODES);
    build_csr(1);
    k_spmm_ln_relu<<<gRow, 256, 0, stream>>>(HA16, row_ptr, scol, sval, b2, ln_g, ln_b, HB16);
    // layer 3
    k_gemm_slab<NHID, true><<<gGemm, 512, 0, stream>>>(HB16, Wf3, HA16, N_NODES);
    build_csr(2);
    k_spmm_ln_relu<<<gRow, 256, 0, stream>>>(HA16, row_ptr, scol, sval, b3, ln_g, ln_b, HB16);
    // output
    k_out<<<gRow, 256, 0, stream>>>(HB16, Wout, bout, out);
}